// Round 10
// baseline (123.117 us; speedup 1.0000x reference)
//
#include <hip/hip_runtime.h>
#include <math.h>

#define LDIM 4096
#define CDIM 64
#define NB 4
#define TL 64                     // k_spatial tile (unchanged, proven)
#define NBLK (LDIM / TL)          // 64
#define TLF 32                    // k_front tile (2 blocks/CU to break lockstep)
#define NBLKF (LDIM / TLF)        // 128
#define NBLOCKS (NB * NBLK)       // 256 (k_spatial blocks -> spB rows)
#define EPS 1e-5f
#define XS 68                     // q/v LDS row stride
#define XSF 36                    // xe/hs row stride for TLF=32 (9 float4)

// workspace layout (float offsets)
#define K_OFF 0                                   // k: [B][C][L]
#define Y_OFF (NB * CDIM * LDIM)                  // y: [B][C][L]
#define P_OFF (2 * NB * CDIM * LDIM)              // M partials: [NB*NBLKF][C*C]
#define M_OFF (P_OFF + NB * NBLKF * CDIM * CDIM)  // M: [B][C*C]
#define SP_OFF (M_OFF + NB * CDIM * CDIM)         // BN partials: [NBLOCKS][2*C]

__device__ __forceinline__ float elu1(float t) { return t > 0.f ? t : expm1f(t); }

// ---------------------------------------------------------------------------
// Kernel 1: ELU -> circular conv3 -> QKV -> (k to global, partial M = v q^T)
// grid (NBLKF, NB) = 512 blocks x 512 thr = 2 blocks/CU (waves of the two
// blocks are NOT barrier-locked -> load latency of one block hides under the
// other's FMA phases; R5 measured 1-block/CU lockstep at VALUBusy 23%).
// Thread = (1 out-channel c, 4 positions p0..p0+3).
// ---------------------------------------------------------------------------
__global__ __launch_bounds__(512, 4) void k_front(
    const float* __restrict__ x,
    const float* __restrict__ conv_w, const float* __restrict__ conv_b,
    const float* __restrict__ wq, const float* __restrict__ bq,
    const float* __restrict__ wk, const float* __restrict__ bk,
    const float* __restrict__ wv, const float* __restrict__ bv,
    float* __restrict__ k_ws, float* __restrict__ P_ws)
{
    __shared__ alignas(16) float xe[CDIM][XSF];   // col = pos+1 (1..32), halo 0,33
    __shared__ alignas(16) float hs[CDIM][XSF];   // col = pos 0..31
    __shared__ alignas(16) float qsT[TLF][XS];    // [pos][c]
    __shared__ alignas(16) float vsT[TLF][XS];

    const int b   = blockIdx.y;
    const int l0  = blockIdx.x * TLF;
    const int tid = threadIdx.x;       // 0..511
    const int c   = tid >> 3;          // out-channel 0..63
    const int p0  = (tid & 7) << 2;    // position group 0..28

    const float* xb = x + (size_t)b * CDIM * LDIM;

    // P1: stage elu(x) tile (col = pos+1) + circular halo cols 0 and 33
    {
        float4 xv = *reinterpret_cast<const float4*>(xb + (size_t)c * LDIM + l0 + p0);
        xe[c][p0 + 1] = elu1(xv.x);
        xe[c][p0 + 2] = elu1(xv.y);
        xe[c][p0 + 3] = elu1(xv.z);
        xe[c][p0 + 4] = elu1(xv.w);
        if (tid < CDIM)
            xe[tid][0] = elu1(xb[(size_t)tid * LDIM + ((l0 - 1) & (LDIM - 1))]);
        else if (tid < 2 * CDIM)
            xe[tid - CDIM][TLF + 1] =
                elu1(xb[(size_t)(tid - CDIM) * LDIM + ((l0 + TLF) & (LDIM - 1))]);
    }
    __syncthreads();

    // P2: conv3. Direct conv_w loads (48B chunk at c*192 + i4*12, 16B-aligned).
    float hacc[4];
    {
        float cb = conv_b[c];
        hacc[0] = hacc[1] = hacc[2] = hacc[3] = cb;
    }
#pragma unroll 2
    for (int i4 = 0; i4 < 16; ++i4) {
        const float4* wrow = (const float4*)(conv_w + (size_t)c * 192 + i4 * 12);
        float4 f0 = wrow[0], f1 = wrow[1], f2 = wrow[2];
        float wx[4], wy[4], wz[4];
        wx[0] = f0.x; wy[0] = f0.y; wz[0] = f0.z;   // di=0: taps 0,1,2
        wx[1] = f0.w; wy[1] = f1.x; wz[1] = f1.y;   // di=1
        wx[2] = f1.z; wy[2] = f1.w; wz[2] = f2.x;   // di=2
        wx[3] = f2.y; wy[3] = f2.z; wz[3] = f2.w;   // di=3
#pragma unroll
        for (int di = 0; di < 4; ++di) {
            const float* xr = &xe[i4 * 4 + di][p0];
            float4 a  = *reinterpret_cast<const float4*>(xr);      // cols p0..p0+3
            float2 e2 = *reinterpret_cast<const float2*>(xr + 4);  // cols p0+4,p0+5
            hacc[0] = fmaf(wx[di], a.x, fmaf(wy[di], a.y, fmaf(wz[di], a.z,  hacc[0])));
            hacc[1] = fmaf(wx[di], a.y, fmaf(wy[di], a.z, fmaf(wz[di], a.w,  hacc[1])));
            hacc[2] = fmaf(wx[di], a.z, fmaf(wy[di], a.w, fmaf(wz[di], e2.x, hacc[2])));
            hacc[3] = fmaf(wx[di], a.w, fmaf(wy[di], e2.x, fmaf(wz[di], e2.y, hacc[3])));
        }
    }
    *reinterpret_cast<float4*>(&hs[c][p0]) =
        make_float4(hacc[0], hacc[1], hacc[2], hacc[3]);
    __syncthreads();

    // P3: QKV. Per i4: 3 weight float4 + 4 b128 h broadcasts feed 48 FMAs.
    const float4* wq4 = (const float4*)wq;
    const float4* wk4 = (const float4*)wk;
    const float4* wv4 = (const float4*)wv;
    float qa[4], ka[4], va[4];
    {
        float t;
        t = bq[c]; qa[0] = qa[1] = qa[2] = qa[3] = t;
        t = bk[c]; ka[0] = ka[1] = ka[2] = ka[3] = t;
        t = bv[c]; va[0] = va[1] = va[2] = va[3] = t;
    }
#pragma unroll 2
    for (int i4 = 0; i4 < 16; ++i4) {
        float4 aq = wq4[c * 16 + i4];
        float4 ak = wk4[c * 16 + i4];
        float4 av = wv4[c * 16 + i4];
        float4 h0 = *reinterpret_cast<const float4*>(&hs[i4 * 4 + 0][p0]);
        float4 h1 = *reinterpret_cast<const float4*>(&hs[i4 * 4 + 1][p0]);
        float4 h2 = *reinterpret_cast<const float4*>(&hs[i4 * 4 + 2][p0]);
        float4 h3 = *reinterpret_cast<const float4*>(&hs[i4 * 4 + 3][p0]);
        qa[0] = fmaf(aq.x, h0.x, fmaf(aq.y, h1.x, fmaf(aq.z, h2.x, fmaf(aq.w, h3.x, qa[0]))));
        qa[1] = fmaf(aq.x, h0.y, fmaf(aq.y, h1.y, fmaf(aq.z, h2.y, fmaf(aq.w, h3.y, qa[1]))));
        qa[2] = fmaf(aq.x, h0.z, fmaf(aq.y, h1.z, fmaf(aq.z, h2.z, fmaf(aq.w, h3.z, qa[2]))));
        qa[3] = fmaf(aq.x, h0.w, fmaf(aq.y, h1.w, fmaf(aq.z, h2.w, fmaf(aq.w, h3.w, qa[3]))));
        ka[0] = fmaf(ak.x, h0.x, fmaf(ak.y, h1.x, fmaf(ak.z, h2.x, fmaf(ak.w, h3.x, ka[0]))));
        ka[1] = fmaf(ak.x, h0.y, fmaf(ak.y, h1.y, fmaf(ak.z, h2.y, fmaf(ak.w, h3.y, ka[1]))));
        ka[2] = fmaf(ak.x, h0.z, fmaf(ak.y, h1.z, fmaf(ak.z, h2.z, fmaf(ak.w, h3.z, ka[2]))));
        ka[3] = fmaf(ak.x, h0.w, fmaf(ak.y, h1.w, fmaf(ak.z, h2.w, fmaf(ak.w, h3.w, ka[3]))));
        va[0] = fmaf(av.x, h0.x, fmaf(av.y, h1.x, fmaf(av.z, h2.x, fmaf(av.w, h3.x, va[0]))));
        va[1] = fmaf(av.x, h0.y, fmaf(av.y, h1.y, fmaf(av.z, h2.y, fmaf(av.w, h3.y, va[1]))));
        va[2] = fmaf(av.x, h0.z, fmaf(av.y, h1.z, fmaf(av.z, h2.z, fmaf(av.w, h3.z, va[2]))));
        va[3] = fmaf(av.x, h0.w, fmaf(av.y, h1.w, fmaf(av.z, h2.w, fmaf(av.w, h3.w, va[3]))));
    }
    *reinterpret_cast<float4*>(k_ws + ((size_t)b * CDIM + c) * LDIM + l0 + p0) =
        make_float4(ka[0], ka[1], ka[2], ka[3]);
    qsT[p0 + 0][c] = qa[0]; qsT[p0 + 1][c] = qa[1];
    qsT[p0 + 2][c] = qa[2]; qsT[p0 + 3][c] = qa[3];
    vsT[p0 + 0][c] = va[0]; vsT[p0 + 1][c] = va[1];
    vsT[p0 + 2][c] = va[2]; vsT[p0 + 3][c] = va[3];
    __syncthreads();

    // P4: partial M[cv][cq] = sum_l v[cv][l]*q[cq][l]; thread owns 1x8 tile.
    const int cv  = tid >> 3;         // 0..63
    const int cq0 = (tid & 7) * 8;    // 0..56
    float m[8] = {0.f, 0.f, 0.f, 0.f, 0.f, 0.f, 0.f, 0.f};
    for (int l = 0; l < TLF; ++l) {
        const float  vv = vsT[l][cv];                                   // broadcast
        const float4 qA = *reinterpret_cast<const float4*>(&qsT[l][cq0]);
        const float4 qB = *reinterpret_cast<const float4*>(&qsT[l][cq0 + 4]);
        m[0] = fmaf(vv, qA.x, m[0]); m[1] = fmaf(vv, qA.y, m[1]);
        m[2] = fmaf(vv, qA.z, m[2]); m[3] = fmaf(vv, qA.w, m[3]);
        m[4] = fmaf(vv, qB.x, m[4]); m[5] = fmaf(vv, qB.y, m[5]);
        m[6] = fmaf(vv, qB.z, m[6]); m[7] = fmaf(vv, qB.w, m[7]);
    }
    float4* Pb = (float4*)(P_ws + ((size_t)b * NBLKF + blockIdx.x) * CDIM * CDIM);
    Pb[cv * (CDIM / 4) + (cq0 >> 2) + 0] = make_float4(m[0], m[1], m[2], m[3]);
    Pb[cv * (CDIM / 4) + (cq0 >> 2) + 1] = make_float4(m[4], m[5], m[6], m[7]);
}

// ---------------------------------------------------------------------------
// Kernel 1b: reduce 128 partials -> M[b][c][c'].  16 blocks x 256 threads.
// ---------------------------------------------------------------------------
__global__ __launch_bounds__(256) void k_reduceM(
    const float* __restrict__ P_ws, float* __restrict__ M_ws)
{
    const int b  = blockIdx.x >> 2;
    const int e4 = (blockIdx.x & 3) * 256 + threadIdx.x;
    const float4* Pf4 = (const float4*)P_ws + (size_t)b * NBLKF * (CDIM * CDIM / 4);
    float4 s0 = make_float4(0, 0, 0, 0), s1 = s0, s2 = s0, s3 = s0;
    for (int blk = 0; blk < NBLKF; blk += 4) {
        float4 p0 = Pf4[(size_t)(blk + 0) * (CDIM * CDIM / 4) + e4];
        float4 p1 = Pf4[(size_t)(blk + 1) * (CDIM * CDIM / 4) + e4];
        float4 p2 = Pf4[(size_t)(blk + 2) * (CDIM * CDIM / 4) + e4];
        float4 p3 = Pf4[(size_t)(blk + 3) * (CDIM * CDIM / 4) + e4];
        s0.x += p0.x; s0.y += p0.y; s0.z += p0.z; s0.w += p0.w;
        s1.x += p1.x; s1.y += p1.y; s1.z += p1.z; s1.w += p1.w;
        s2.x += p2.x; s2.y += p2.y; s2.z += p2.z; s2.w += p2.w;
        s3.x += p3.x; s3.y += p3.y; s3.z += p3.z; s3.w += p3.w;
    }
    float4 s = make_float4((s0.x + s1.x) + (s2.x + s3.x),
                           (s0.y + s1.y) + (s2.y + s3.y),
                           (s0.z + s1.z) + (s2.z + s3.z),
                           (s0.w + s1.w) + (s2.w + s3.w));
    ((float4*)M_ws)[(size_t)b * (CDIM * CDIM / 4) + e4] = s;
}

// ---------------------------------------------------------------------------
// Kernel 2: y = M k + x; BN partials. (R7-proven structure, unchanged.)
// ---------------------------------------------------------------------------
__global__ __launch_bounds__(1024, 4) void k_spatial(
    const float* __restrict__ x, const float* __restrict__ k_ws,
    const float* __restrict__ M_ws, float* __restrict__ y_ws,
    float* __restrict__ spB)
{
    __shared__ alignas(16) float kl[CDIM][XS];
    __shared__ alignas(16) float Ms[CDIM][XS];
    const int b   = blockIdx.y;
    const int l0  = blockIdx.x * TL;
    const int tid = threadIdx.x;
    const int c   = tid >> 4;
    const int p0  = (tid & 15) << 2;

    *reinterpret_cast<float4*>(&Ms[c][p0]) =
        ((const float4*)M_ws)[(size_t)b * (CDIM * CDIM / 4) + tid];
    *reinterpret_cast<float4*>(&kl[c][p0]) =
        *reinterpret_cast<const float4*>(k_ws + ((size_t)b * CDIM + c) * LDIM + l0 + p0);
    __syncthreads();

    float4 acc = *reinterpret_cast<const float4*>(
        x + ((size_t)b * CDIM + c) * LDIM + l0 + p0);
#pragma unroll 2
    for (int i4 = 0; i4 < 16; ++i4) {
        float4 mv = *reinterpret_cast<const float4*>(&Ms[c][i4 * 4]);
        float4 k0 = *reinterpret_cast<const float4*>(&kl[i4 * 4 + 0][p0]);
        float4 k1 = *reinterpret_cast<const float4*>(&kl[i4 * 4 + 1][p0]);
        float4 k2 = *reinterpret_cast<const float4*>(&kl[i4 * 4 + 2][p0]);
        float4 k3 = *reinterpret_cast<const float4*>(&kl[i4 * 4 + 3][p0]);
        acc.x = fmaf(mv.x, k0.x, fmaf(mv.y, k1.x, fmaf(mv.z, k2.x, fmaf(mv.w, k3.x, acc.x))));
        acc.y = fmaf(mv.x, k0.y, fmaf(mv.y, k1.y, fmaf(mv.z, k2.y, fmaf(mv.w, k3.y, acc.y))));
        acc.z = fmaf(mv.x, k0.z, fmaf(mv.y, k1.z, fmaf(mv.z, k2.z, fmaf(mv.w, k3.z, acc.z))));
        acc.w = fmaf(mv.x, k0.w, fmaf(mv.y, k1.w, fmaf(mv.z, k2.w, fmaf(mv.w, k3.w, acc.w))));
    }
    *reinterpret_cast<float4*>(y_ws + ((size_t)b * CDIM + c) * LDIM + l0 + p0) = acc;

    const int blk = blockIdx.y * NBLK + blockIdx.x;
    float s  = (acc.x + acc.y) + (acc.z + acc.w);
    float s2 = fmaf(acc.x, acc.x, fmaf(acc.y, acc.y,
               fmaf(acc.z, acc.z, acc.w * acc.w)));
    for (int off = 8; off; off >>= 1) {
        s  += __shfl_down(s, off);
        s2 += __shfl_down(s2, off);
    }
    if ((tid & 15) == 0) {
        spB[(size_t)blk * (2 * CDIM) + c] = s;
        spB[(size_t)blk * (2 * CDIM) + CDIM + c] = s2;
    }
}

// ---------------------------------------------------------------------------
// Kernel 3 (merged reduceS+norm): each of 256 blocks redundantly reduces
// spB [256][128] in LDS (33MB aggregate L2 ~ 1us), then normalizes its
// 1024-float4 slice of y. Removes one dispatch boundary + serial reducer.
// ---------------------------------------------------------------------------
__global__ __launch_bounds__(1024) void k_normS(
    const float* __restrict__ y_ws, const float* __restrict__ spB,
    const float* __restrict__ gamma, const float* __restrict__ beta,
    float* __restrict__ out)
{
    __shared__ float red[8][128];
    __shared__ float sums2[2 * CDIM];
    const int tid = threadIdx.x;

    {   // reduce spB
        const int t = tid & 127;
        const int g = tid >> 7;          // 0..7, 32 rows each
        float s0 = 0.f, s1 = 0.f;
        const int r0 = g * 32;
        for (int r = r0; r < r0 + 32; r += 2) {
            s0 += spB[(size_t)(r + 0) * (2 * CDIM) + t];
            s1 += spB[(size_t)(r + 1) * (2 * CDIM) + t];
        }
        red[g][t] = s0 + s1;
    }
    __syncthreads();
    if (tid < 128)
        sums2[tid] = ((red[0][tid] + red[1][tid]) + (red[2][tid] + red[3][tid]))
                   + ((red[4][tid] + red[5][tid]) + (red[6][tid] + red[7][tid]));
    __syncthreads();

    const int idx = blockIdx.x * 1024 + tid;       // float4 index
    const int c   = (idx >> 10) & (CDIM - 1);      // 1024 float4 per (b,c) row
    const float inv = 1.f / (float)(NB * LDIM);
    float mean = sums2[c] * inv;
    float var  = fmaf(-mean, mean, sums2[CDIM + c] * inv);
    float rstd = 1.f / sqrtf(var + EPS);
    float g    = gamma[c] * rstd;
    float bb   = fmaf(-mean, g, beta[c]);

    float4 v = ((const float4*)y_ws)[idx];
    float4 o;
    o.x = fmaf(v.x, g, bb);
    o.y = fmaf(v.y, g, bb);
    o.z = fmaf(v.z, g, bb);
    o.w = fmaf(v.w, g, bb);
    ((float4*)out)[idx] = o;
}

// ---------------------------------------------------------------------------
extern "C" void kernel_launch(void* const* d_in, const int* in_sizes, int n_in,
                              void* d_out, int out_size, void* d_ws, size_t ws_size,
                              hipStream_t stream)
{
    const float* x      = (const float*)d_in[0];
    const float* conv_w = (const float*)d_in[1];
    const float* conv_b = (const float*)d_in[2];
    const float* wq     = (const float*)d_in[3];
    const float* bq     = (const float*)d_in[4];
    const float* wk     = (const float*)d_in[5];
    const float* bk     = (const float*)d_in[6];
    const float* wv     = (const float*)d_in[7];
    const float* bv     = (const float*)d_in[8];
    const float* gamma  = (const float*)d_in[9];
    const float* beta   = (const float*)d_in[10];

    float* ws   = (float*)d_ws;
    float* k_ws = ws + K_OFF;
    float* y_ws = ws + Y_OFF;
    float* P_ws = ws + P_OFF;
    float* M_ws = ws + M_OFF;
    float* spB  = ws + SP_OFF;

    dim3 gridF(NBLKF, NB);                 // 512 blocks, 2/CU
    dim3 gridS(NBLK, NB);                  // 256 blocks
    k_front<<<gridF, 512, 0, stream>>>(x, conv_w, conv_b, wq, bq, wk, bk,
                                       wv, bv, k_ws, P_ws);
    k_reduceM<<<16, 256, 0, stream>>>(P_ws, M_ws);
    k_spatial<<<gridS, 1024, 0, stream>>>(x, k_ws, M_ws, y_ws, spB);
    k_normS<<<NB * CDIM * LDIM / 4096, 1024, 0, stream>>>(y_ws, spB, gamma, beta,
                                                          (float*)d_out);
}

// Round 11
// 120.924 us; speedup vs baseline: 1.0181x; 1.0181x over previous
//
#include <hip/hip_runtime.h>
#include <math.h>

#define LDIM 4096
#define CDIM 64
#define NB 4
#define TL 64
#define NBLK (LDIM / TL)          // 64 tiles per batch
#define NBLOCKS (NB * NBLK)       // 256
#define EPS 1e-5f
#define XS 68                     // LDS row stride (17 float4 -> 16B-aligned rows)

// workspace layout (float offsets)
#define K_OFF 0                                   // k: [B][C][L]
#define Y_OFF (NB * CDIM * LDIM)                  // y: [B][C][L]
#define P_OFF (2 * NB * CDIM * LDIM)              // M partials: [NB*NBLK][C*C]
#define SP_OFF (P_OFF + NB * NBLK * CDIM * CDIM)  // BN partials: [NBLOCKS][2*C]

__device__ __forceinline__ float elu1(float t) { return t > 0.f ? t : expm1f(t); }

// ---------------------------------------------------------------------------
// Kernel 1: ELU -> circular conv3 -> QKV -> (k to global, partial M = v q^T)
// EXACT R9 configuration (proven 122.8us total): grid (NBLK, NB), block 1024,
// thread = (1 out-channel, 4 positions), direct 16B-aligned conv_w loads.
// ---------------------------------------------------------------------------
__global__ __launch_bounds__(1024, 4) void k_front(
    const float* __restrict__ x,
    const float* __restrict__ conv_w, const float* __restrict__ conv_b,
    const float* __restrict__ wq, const float* __restrict__ bq,
    const float* __restrict__ wk, const float* __restrict__ bk,
    const float* __restrict__ wv, const float* __restrict__ bv,
    float* __restrict__ k_ws, float* __restrict__ P_ws)
{
    __shared__ alignas(16) float xe[CDIM][XS];   // col = pos+1 (1..64), halo 0,65
    __shared__ alignas(16) float hs[CDIM][XS];   // col = pos
    __shared__ alignas(16) float qsT[TL][XS];    // [pos][c]
    __shared__ alignas(16) float vsT[TL][XS];

    const int b   = blockIdx.y;
    const int l0  = blockIdx.x * TL;
    const int tid = threadIdx.x;
    const int c   = tid >> 4;          // out-channel 0..63
    const int p0  = (tid & 15) << 2;   // position group 0..60

    const float* xb = x + (size_t)b * CDIM * LDIM;

    // P1: stage elu(x) tile (col = pos+1) + circular halo cols 0 and 65
    {
        float4 xv = *reinterpret_cast<const float4*>(xb + (size_t)c * LDIM + l0 + p0);
        xe[c][p0 + 1] = elu1(xv.x);
        xe[c][p0 + 2] = elu1(xv.y);
        xe[c][p0 + 3] = elu1(xv.z);
        xe[c][p0 + 4] = elu1(xv.w);
        if (tid < CDIM)
            xe[tid][0] = elu1(xb[(size_t)tid * LDIM + ((l0 - 1) & (LDIM - 1))]);
        else if (tid < 2 * CDIM)
            xe[tid - CDIM][TL + 1] =
                elu1(xb[(size_t)(tid - CDIM) * LDIM + ((l0 + TL) & (LDIM - 1))]);
    }
    __syncthreads();

    // P2: conv3. Direct conv_w loads (48B chunk at c*192 + i4*12, 16B-aligned).
    float hacc[4];
    {
        float cb = conv_b[c];
        hacc[0] = hacc[1] = hacc[2] = hacc[3] = cb;
    }
#pragma unroll 2
    for (int i4 = 0; i4 < 16; ++i4) {
        const float4* wrow = (const float4*)(conv_w + (size_t)c * 192 + i4 * 12);
        float4 f0 = wrow[0], f1 = wrow[1], f2 = wrow[2];
        float wx[4], wy[4], wz[4];
        wx[0] = f0.x; wy[0] = f0.y; wz[0] = f0.z;   // di=0: taps 0,1,2
        wx[1] = f0.w; wy[1] = f1.x; wz[1] = f1.y;   // di=1
        wx[2] = f1.z; wy[2] = f1.w; wz[2] = f2.x;   // di=2
        wx[3] = f2.y; wy[3] = f2.z; wz[3] = f2.w;   // di=3
#pragma unroll
        for (int di = 0; di < 4; ++di) {
            const float* xr = &xe[i4 * 4 + di][p0];
            float4 a  = *reinterpret_cast<const float4*>(xr);      // cols p0..p0+3
            float2 e2 = *reinterpret_cast<const float2*>(xr + 4);  // cols p0+4,p0+5
            hacc[0] = fmaf(wx[di], a.x, fmaf(wy[di], a.y, fmaf(wz[di], a.z,  hacc[0])));
            hacc[1] = fmaf(wx[di], a.y, fmaf(wy[di], a.z, fmaf(wz[di], a.w,  hacc[1])));
            hacc[2] = fmaf(wx[di], a.z, fmaf(wy[di], a.w, fmaf(wz[di], e2.x, hacc[2])));
            hacc[3] = fmaf(wx[di], a.w, fmaf(wy[di], e2.x, fmaf(wz[di], e2.y, hacc[3])));
        }
    }
    *reinterpret_cast<float4*>(&hs[c][p0]) =
        make_float4(hacc[0], hacc[1], hacc[2], hacc[3]);
    __syncthreads();

    // P3: QKV. Per i4: 3 weight float4 + 4 b128 h reads feed 48 FMAs.
    const float4* wq4 = (const float4*)wq;
    const float4* wk4 = (const float4*)wk;
    const float4* wv4 = (const float4*)wv;
    float qa[4], ka[4], va[4];
    {
        float t;
        t = bq[c]; qa[0] = qa[1] = qa[2] = qa[3] = t;
        t = bk[c]; ka[0] = ka[1] = ka[2] = ka[3] = t;
        t = bv[c]; va[0] = va[1] = va[2] = va[3] = t;
    }
#pragma unroll 2
    for (int i4 = 0; i4 < 16; ++i4) {
        float4 aq = wq4[c * 16 + i4];
        float4 ak = wk4[c * 16 + i4];
        float4 av = wv4[c * 16 + i4];
        float4 h0 = *reinterpret_cast<const float4*>(&hs[i4 * 4 + 0][p0]);
        float4 h1 = *reinterpret_cast<const float4*>(&hs[i4 * 4 + 1][p0]);
        float4 h2 = *reinterpret_cast<const float4*>(&hs[i4 * 4 + 2][p0]);
        float4 h3 = *reinterpret_cast<const float4*>(&hs[i4 * 4 + 3][p0]);
        qa[0] = fmaf(aq.x, h0.x, fmaf(aq.y, h1.x, fmaf(aq.z, h2.x, fmaf(aq.w, h3.x, qa[0]))));
        qa[1] = fmaf(aq.x, h0.y, fmaf(aq.y, h1.y, fmaf(aq.z, h2.y, fmaf(aq.w, h3.y, qa[1]))));
        qa[2] = fmaf(aq.x, h0.z, fmaf(aq.y, h1.z, fmaf(aq.z, h2.z, fmaf(aq.w, h3.z, qa[2]))));
        qa[3] = fmaf(aq.x, h0.w, fmaf(aq.y, h1.w, fmaf(aq.z, h2.w, fmaf(aq.w, h3.w, qa[3]))));
        ka[0] = fmaf(ak.x, h0.x, fmaf(ak.y, h1.x, fmaf(ak.z, h2.x, fmaf(ak.w, h3.x, ka[0]))));
        ka[1] = fmaf(ak.x, h0.y, fmaf(ak.y, h1.y, fmaf(ak.z, h2.y, fmaf(ak.w, h3.y, ka[1]))));
        ka[2] = fmaf(ak.x, h0.z, fmaf(ak.y, h1.z, fmaf(ak.z, h2.z, fmaf(ak.w, h3.z, ka[2]))));
        ka[3] = fmaf(ak.x, h0.w, fmaf(ak.y, h1.w, fmaf(ak.z, h2.w, fmaf(ak.w, h3.w, ka[3]))));
        va[0] = fmaf(av.x, h0.x, fmaf(av.y, h1.x, fmaf(av.z, h2.x, fmaf(av.w, h3.x, va[0]))));
        va[1] = fmaf(av.x, h0.y, fmaf(av.y, h1.y, fmaf(av.z, h2.y, fmaf(av.w, h3.y, va[1]))));
        va[2] = fmaf(av.x, h0.z, fmaf(av.y, h1.z, fmaf(av.z, h2.z, fmaf(av.w, h3.z, va[2]))));
        va[3] = fmaf(av.x, h0.w, fmaf(av.y, h1.w, fmaf(av.z, h2.w, fmaf(av.w, h3.w, va[3]))));
    }
    *reinterpret_cast<float4*>(k_ws + ((size_t)b * CDIM + c) * LDIM + l0 + p0) =
        make_float4(ka[0], ka[1], ka[2], ka[3]);
    qsT[p0 + 0][c] = qa[0]; qsT[p0 + 1][c] = qa[1];
    qsT[p0 + 2][c] = qa[2]; qsT[p0 + 3][c] = qa[3];
    vsT[p0 + 0][c] = va[0]; vsT[p0 + 1][c] = va[1];
    vsT[p0 + 2][c] = va[2]; vsT[p0 + 3][c] = va[3];
    __syncthreads();

    // P4: partial M[cv][cq] = sum_l v[cv][l]*q[cq][l]; thread owns 1x4 tile.
    const int cv  = tid >> 4;         // 0..63
    const int cq0 = (tid & 15) * 4;   // 0..60
    float m0 = 0.f, m1 = 0.f, m2 = 0.f, m3 = 0.f;
    for (int l = 0; l < TL; ++l) {
        const float  vv = vsT[l][cv];
        const float4 qq = *reinterpret_cast<const float4*>(&qsT[l][cq0]);
        m0 = fmaf(vv, qq.x, m0);
        m1 = fmaf(vv, qq.y, m1);
        m2 = fmaf(vv, qq.z, m2);
        m3 = fmaf(vv, qq.w, m3);
    }
    float4* Pb = (float4*)(P_ws + ((size_t)b * NBLK + blockIdx.x) * CDIM * CDIM);
    Pb[cv * (CDIM / 4) + (cq0 >> 2)] = make_float4(m0, m1, m2, m3);
}

// ---------------------------------------------------------------------------
// Kernel 2: reduce M partials in-block -> y = M k + x -> BN partials.
// k_reduceM dispatch ELIMINATED: each block sums its batch's 64 partials
// (1 MB, L2-broadcast across the 64 blocks of the batch) straight into Ms.
// Thread owns one float4 of M (tid): 64 unrolled b128 L2 loads, 8-wave hidden.
// ---------------------------------------------------------------------------
__global__ __launch_bounds__(1024, 4) void k_spatial(
    const float* __restrict__ x, const float* __restrict__ k_ws,
    const float* __restrict__ P_ws, float* __restrict__ y_ws,
    float* __restrict__ spB)
{
    __shared__ alignas(16) float kl[CDIM][XS];
    __shared__ alignas(16) float Ms[CDIM][XS];
    const int b   = blockIdx.y;
    const int l0  = blockIdx.x * TL;
    const int tid = threadIdx.x;
    const int c   = tid >> 4;
    const int p0  = (tid & 15) << 2;

    // reduce the 64 M-partials for batch b; thread owns float4 element 'tid'
    {
        const float4* Pf4 = (const float4*)P_ws + (size_t)b * NBLK * (CDIM * CDIM / 4);
        float4 s0 = make_float4(0, 0, 0, 0), s1 = s0, s2 = s0, s3 = s0;
        for (int blk = 0; blk < NBLK; blk += 4) {
            float4 p0v = Pf4[(size_t)(blk + 0) * (CDIM * CDIM / 4) + tid];
            float4 p1v = Pf4[(size_t)(blk + 1) * (CDIM * CDIM / 4) + tid];
            float4 p2v = Pf4[(size_t)(blk + 2) * (CDIM * CDIM / 4) + tid];
            float4 p3v = Pf4[(size_t)(blk + 3) * (CDIM * CDIM / 4) + tid];
            s0.x += p0v.x; s0.y += p0v.y; s0.z += p0v.z; s0.w += p0v.w;
            s1.x += p1v.x; s1.y += p1v.y; s1.z += p1v.z; s1.w += p1v.w;
            s2.x += p2v.x; s2.y += p2v.y; s2.z += p2v.z; s2.w += p2v.w;
            s3.x += p3v.x; s3.y += p3v.y; s3.z += p3v.z; s3.w += p3v.w;
        }
        *reinterpret_cast<float4*>(&Ms[c][p0]) =
            make_float4((s0.x + s1.x) + (s2.x + s3.x),
                        (s0.y + s1.y) + (s2.y + s3.y),
                        (s0.z + s1.z) + (s2.z + s3.z),
                        (s0.w + s1.w) + (s2.w + s3.w));
    }
    *reinterpret_cast<float4*>(&kl[c][p0]) =
        *reinterpret_cast<const float4*>(k_ws + ((size_t)b * CDIM + c) * LDIM + l0 + p0);
    __syncthreads();

    float4 acc = *reinterpret_cast<const float4*>(
        x + ((size_t)b * CDIM + c) * LDIM + l0 + p0);
#pragma unroll 2
    for (int i4 = 0; i4 < 16; ++i4) {
        float4 mv = *reinterpret_cast<const float4*>(&Ms[c][i4 * 4]);
        float4 k0 = *reinterpret_cast<const float4*>(&kl[i4 * 4 + 0][p0]);
        float4 k1 = *reinterpret_cast<const float4*>(&kl[i4 * 4 + 1][p0]);
        float4 k2 = *reinterpret_cast<const float4*>(&kl[i4 * 4 + 2][p0]);
        float4 k3 = *reinterpret_cast<const float4*>(&kl[i4 * 4 + 3][p0]);
        acc.x = fmaf(mv.x, k0.x, fmaf(mv.y, k1.x, fmaf(mv.z, k2.x, fmaf(mv.w, k3.x, acc.x))));
        acc.y = fmaf(mv.x, k0.y, fmaf(mv.y, k1.y, fmaf(mv.z, k2.y, fmaf(mv.w, k3.y, acc.y))));
        acc.z = fmaf(mv.x, k0.z, fmaf(mv.y, k1.z, fmaf(mv.z, k2.z, fmaf(mv.w, k3.z, acc.z))));
        acc.w = fmaf(mv.x, k0.w, fmaf(mv.y, k1.w, fmaf(mv.z, k2.w, fmaf(mv.w, k3.w, acc.w))));
    }
    *reinterpret_cast<float4*>(y_ws + ((size_t)b * CDIM + c) * LDIM + l0 + p0) = acc;

    const int blk = blockIdx.y * NBLK + blockIdx.x;
    float s  = (acc.x + acc.y) + (acc.z + acc.w);
    float s2 = fmaf(acc.x, acc.x, fmaf(acc.y, acc.y,
               fmaf(acc.z, acc.z, acc.w * acc.w)));
    for (int off = 8; off; off >>= 1) {
        s  += __shfl_down(s, off);
        s2 += __shfl_down(s2, off);
    }
    if ((tid & 15) == 0) {
        spB[(size_t)blk * (2 * CDIM) + c] = s;
        spB[(size_t)blk * (2 * CDIM) + CDIM + c] = s2;
    }
}

// ---------------------------------------------------------------------------
// Kernel 3 (merged reduceS+norm): each of 256 blocks redundantly reduces
// spB [256][128] in LDS, then normalizes its 1024-float4 slice of y.
// ---------------------------------------------------------------------------
__global__ __launch_bounds__(1024) void k_normS(
    const float* __restrict__ y_ws, const float* __restrict__ spB,
    const float* __restrict__ gamma, const float* __restrict__ beta,
    float* __restrict__ out)
{
    __shared__ float red[8][128];
    __shared__ float sums2[2 * CDIM];
    const int tid = threadIdx.x;

    {   // reduce spB
        const int t = tid & 127;
        const int g = tid >> 7;          // 0..7, 32 rows each
        float s0 = 0.f, s1 = 0.f;
        const int r0 = g * 32;
        for (int r = r0; r < r0 + 32; r += 2) {
            s0 += spB[(size_t)(r + 0) * (2 * CDIM) + t];
            s1 += spB[(size_t)(r + 1) * (2 * CDIM) + t];
        }
        red[g][t] = s0 + s1;
    }
    __syncthreads();
    if (tid < 128)
        sums2[tid] = ((red[0][tid] + red[1][tid]) + (red[2][tid] + red[3][tid]))
                   + ((red[4][tid] + red[5][tid]) + (red[6][tid] + red[7][tid]));
    __syncthreads();

    const int idx = blockIdx.x * 1024 + tid;       // float4 index
    const int c   = (idx >> 10) & (CDIM - 1);      // 1024 float4 per (b,c) row
    const float inv = 1.f / (float)(NB * LDIM);
    float mean = sums2[c] * inv;
    float var  = fmaf(-mean, mean, sums2[CDIM + c] * inv);
    float rstd = 1.f / sqrtf(var + EPS);
    float g    = gamma[c] * rstd;
    float bb   = fmaf(-mean, g, beta[c]);

    float4 v = ((const float4*)y_ws)[idx];
    float4 o;
    o.x = fmaf(v.x, g, bb);
    o.y = fmaf(v.y, g, bb);
    o.z = fmaf(v.z, g, bb);
    o.w = fmaf(v.w, g, bb);
    ((float4*)out)[idx] = o;
}

// ---------------------------------------------------------------------------
extern "C" void kernel_launch(void* const* d_in, const int* in_sizes, int n_in,
                              void* d_out, int out_size, void* d_ws, size_t ws_size,
                              hipStream_t stream)
{
    const float* x      = (const float*)d_in[0];
    const float* conv_w = (const float*)d_in[1];
    const float* conv_b = (const float*)d_in[2];
    const float* wq     = (const float*)d_in[3];
    const float* bq     = (const float*)d_in[4];
    const float* wk     = (const float*)d_in[5];
    const float* bk     = (const float*)d_in[6];
    const float* wv     = (const float*)d_in[7];
    const float* bv     = (const float*)d_in[8];
    const float* gamma  = (const float*)d_in[9];
    const float* beta   = (const float*)d_in[10];

    float* ws   = (float*)d_ws;
    float* k_ws = ws + K_OFF;
    float* y_ws = ws + Y_OFF;
    float* P_ws = ws + P_OFF;
    float* spB  = ws + SP_OFF;

    dim3 grid(NBLK, NB);
    k_front<<<grid, 1024, 0, stream>>>(x, conv_w, conv_b, wq, bq, wk, bk,
                                       wv, bv, k_ws, P_ws);
    k_spatial<<<grid, 1024, 0, stream>>>(x, k_ws, P_ws, y_ws, spB);
    k_normS<<<NB * CDIM * LDIM / 4096, 1024, 0, stream>>>(y_ws, spB, gamma, beta,
                                                          (float*)d_out);
}

// Round 12
// 117.369 us; speedup vs baseline: 1.0490x; 1.0303x over previous
//
#include <hip/hip_runtime.h>
#include <math.h>

#define LDIM 4096
#define CDIM 64
#define NB 4
#define TL 64
#define NBLK (LDIM / TL)          // 64 tiles per batch
#define NBLOCKS (NB * NBLK)       // 256
#define EPS 1e-5f
#define XS 68                     // LDS row stride (17 float4 -> 16B-aligned rows)
#define WSTR 17                   // weight LDS stride (float4) -> bank-spread

// workspace layout (float offsets)
#define K_OFF 0                                   // k: [B][C][L]
#define Y_OFF (NB * CDIM * LDIM)                  // y: [B][C][L]
#define P_OFF (2 * NB * CDIM * LDIM)              // M partials: [NB*NBLK][C*C]
#define SP_OFF (P_OFF + NB * NBLK * CDIM * CDIM)  // BN partials: [NBLOCKS][2*C]

__device__ __forceinline__ float elu1(float t) { return t > 0.f ? t : expm1f(t); }

// ---------------------------------------------------------------------------
// Kernel 1: ELU -> circular conv3 -> QKV -> (k to global, partial M = v q^T)
// R9 structure + QKV weights staged in LDS (51 KB): the 48 per-thread weight
// float4 VMEM loads (16x redundant across threads sharing c, ~200cy L2 each)
// become conflict-free LDS broadcasts (~12cy). Staged before P1's barrier.
// ---------------------------------------------------------------------------
__global__ __launch_bounds__(1024, 4) void k_front(
    const float* __restrict__ x,
    const float* __restrict__ conv_w, const float* __restrict__ conv_b,
    const float* __restrict__ wq, const float* __restrict__ bq,
    const float* __restrict__ wk, const float* __restrict__ bk,
    const float* __restrict__ wv, const float* __restrict__ bv,
    float* __restrict__ k_ws, float* __restrict__ P_ws)
{
    __shared__ alignas(16) float xe[CDIM][XS];   // col = pos+1 (1..64), halo 0,65
    __shared__ alignas(16) float hs[CDIM][XS];   // col = pos
    __shared__ alignas(16) float qsT[TL][XS];    // [pos][c]
    __shared__ alignas(16) float vsT[TL][XS];
    __shared__ alignas(16) float4 wls[3 * CDIM * WSTR];  // q,k,v: [mat][c][i4]

    const int b   = blockIdx.y;
    const int l0  = blockIdx.x * TL;
    const int tid = threadIdx.x;
    const int c   = tid >> 4;          // out-channel 0..63
    const int p0  = (tid & 15) << 2;   // position group 0..60

    const float* xb = x + (size_t)b * CDIM * LDIM;

    // P0: stage QKV weights -> LDS (3*1024 float4, 3 per thread, coalesced)
    {
        const float4* wq4 = (const float4*)wq;
        const float4* wk4 = (const float4*)wk;
        const float4* wv4 = (const float4*)wv;
        for (int i = tid; i < 3 * CDIM * 16; i += 1024) {
            const int mat = i >> 10;          // 0..2
            const int rem = i & 1023;         // c*16 + i4
            const int cc  = rem >> 4;
            const int ii  = rem & 15;
            const float4 v = (mat == 0) ? wq4[rem] : (mat == 1) ? wk4[rem] : wv4[rem];
            wls[mat * (CDIM * WSTR) + cc * WSTR + ii] = v;
        }
    }

    // P1: stage elu(x) tile (col = pos+1) + circular halo cols 0 and 65
    {
        float4 xv = *reinterpret_cast<const float4*>(xb + (size_t)c * LDIM + l0 + p0);
        xe[c][p0 + 1] = elu1(xv.x);
        xe[c][p0 + 2] = elu1(xv.y);
        xe[c][p0 + 3] = elu1(xv.z);
        xe[c][p0 + 4] = elu1(xv.w);
        if (tid < CDIM)
            xe[tid][0] = elu1(xb[(size_t)tid * LDIM + ((l0 - 1) & (LDIM - 1))]);
        else if (tid < 2 * CDIM)
            xe[tid - CDIM][TL + 1] =
                elu1(xb[(size_t)(tid - CDIM) * LDIM + ((l0 + TL) & (LDIM - 1))]);
    }
    __syncthreads();

    // P2: conv3. Direct conv_w loads (48B chunk at c*192 + i4*12, 16B-aligned).
    float hacc[4];
    {
        float cb = conv_b[c];
        hacc[0] = hacc[1] = hacc[2] = hacc[3] = cb;
    }
#pragma unroll 2
    for (int i4 = 0; i4 < 16; ++i4) {
        const float4* wrow = (const float4*)(conv_w + (size_t)c * 192 + i4 * 12);
        float4 f0 = wrow[0], f1 = wrow[1], f2 = wrow[2];
        float wx[4], wy[4], wz[4];
        wx[0] = f0.x; wy[0] = f0.y; wz[0] = f0.z;   // di=0: taps 0,1,2
        wx[1] = f0.w; wy[1] = f1.x; wz[1] = f1.y;   // di=1
        wx[2] = f1.z; wy[2] = f1.w; wz[2] = f2.x;   // di=2
        wx[3] = f2.y; wy[3] = f2.z; wz[3] = f2.w;   // di=3
#pragma unroll
        for (int di = 0; di < 4; ++di) {
            const float* xr = &xe[i4 * 4 + di][p0];
            float4 a  = *reinterpret_cast<const float4*>(xr);      // cols p0..p0+3
            float2 e2 = *reinterpret_cast<const float2*>(xr + 4);  // cols p0+4,p0+5
            hacc[0] = fmaf(wx[di], a.x, fmaf(wy[di], a.y, fmaf(wz[di], a.z,  hacc[0])));
            hacc[1] = fmaf(wx[di], a.y, fmaf(wy[di], a.z, fmaf(wz[di], a.w,  hacc[1])));
            hacc[2] = fmaf(wx[di], a.z, fmaf(wy[di], a.w, fmaf(wz[di], e2.x, hacc[2])));
            hacc[3] = fmaf(wx[di], a.w, fmaf(wy[di], e2.x, fmaf(wz[di], e2.y, hacc[3])));
        }
    }
    *reinterpret_cast<float4*>(&hs[c][p0]) =
        make_float4(hacc[0], hacc[1], hacc[2], hacc[3]);
    __syncthreads();

    // P3: QKV. Per i4: 3 LDS weight broadcasts + 4 b128 h reads feed 48 FMAs.
    const int wbase = c * WSTR;
    float qa[4], ka[4], va[4];
    {
        float t;
        t = bq[c]; qa[0] = qa[1] = qa[2] = qa[3] = t;
        t = bk[c]; ka[0] = ka[1] = ka[2] = ka[3] = t;
        t = bv[c]; va[0] = va[1] = va[2] = va[3] = t;
    }
#pragma unroll 2
    for (int i4 = 0; i4 < 16; ++i4) {
        float4 aq = wls[wbase + i4];
        float4 ak = wls[(CDIM * WSTR) + wbase + i4];
        float4 av = wls[2 * (CDIM * WSTR) + wbase + i4];
        float4 h0 = *reinterpret_cast<const float4*>(&hs[i4 * 4 + 0][p0]);
        float4 h1 = *reinterpret_cast<const float4*>(&hs[i4 * 4 + 1][p0]);
        float4 h2 = *reinterpret_cast<const float4*>(&hs[i4 * 4 + 2][p0]);
        float4 h3 = *reinterpret_cast<const float4*>(&hs[i4 * 4 + 3][p0]);
        qa[0] = fmaf(aq.x, h0.x, fmaf(aq.y, h1.x, fmaf(aq.z, h2.x, fmaf(aq.w, h3.x, qa[0]))));
        qa[1] = fmaf(aq.x, h0.y, fmaf(aq.y, h1.y, fmaf(aq.z, h2.y, fmaf(aq.w, h3.y, qa[1]))));
        qa[2] = fmaf(aq.x, h0.z, fmaf(aq.y, h1.z, fmaf(aq.z, h2.z, fmaf(aq.w, h3.z, qa[2]))));
        qa[3] = fmaf(aq.x, h0.w, fmaf(aq.y, h1.w, fmaf(aq.z, h2.w, fmaf(aq.w, h3.w, qa[3]))));
        ka[0] = fmaf(ak.x, h0.x, fmaf(ak.y, h1.x, fmaf(ak.z, h2.x, fmaf(ak.w, h3.x, ka[0]))));
        ka[1] = fmaf(ak.x, h0.y, fmaf(ak.y, h1.y, fmaf(ak.z, h2.y, fmaf(ak.w, h3.y, ka[1]))));
        ka[2] = fmaf(ak.x, h0.z, fmaf(ak.y, h1.z, fmaf(ak.z, h2.z, fmaf(ak.w, h3.z, ka[2]))));
        ka[3] = fmaf(ak.x, h0.w, fmaf(ak.y, h1.w, fmaf(ak.z, h2.w, fmaf(ak.w, h3.w, ka[3]))));
        va[0] = fmaf(av.x, h0.x, fmaf(av.y, h1.x, fmaf(av.z, h2.x, fmaf(av.w, h3.x, va[0]))));
        va[1] = fmaf(av.x, h0.y, fmaf(av.y, h1.y, fmaf(av.z, h2.y, fmaf(av.w, h3.y, va[1]))));
        va[2] = fmaf(av.x, h0.z, fmaf(av.y, h1.z, fmaf(av.z, h2.z, fmaf(av.w, h3.z, va[2]))));
        va[3] = fmaf(av.x, h0.w, fmaf(av.y, h1.w, fmaf(av.z, h2.w, fmaf(av.w, h3.w, va[3]))));
    }
    *reinterpret_cast<float4*>(k_ws + ((size_t)b * CDIM + c) * LDIM + l0 + p0) =
        make_float4(ka[0], ka[1], ka[2], ka[3]);
    qsT[p0 + 0][c] = qa[0]; qsT[p0 + 1][c] = qa[1];
    qsT[p0 + 2][c] = qa[2]; qsT[p0 + 3][c] = qa[3];
    vsT[p0 + 0][c] = va[0]; vsT[p0 + 1][c] = va[1];
    vsT[p0 + 2][c] = va[2]; vsT[p0 + 3][c] = va[3];
    __syncthreads();

    // P4: partial M[cv][cq] = sum_l v[cv][l]*q[cq][l]; thread owns 1x4 tile.
    const int cv  = tid >> 4;         // 0..63
    const int cq0 = (tid & 15) * 4;   // 0..60
    float m0 = 0.f, m1 = 0.f, m2 = 0.f, m3 = 0.f;
    for (int l = 0; l < TL; ++l) {
        const float  vv = vsT[l][cv];
        const float4 qq = *reinterpret_cast<const float4*>(&qsT[l][cq0]);
        m0 = fmaf(vv, qq.x, m0);
        m1 = fmaf(vv, qq.y, m1);
        m2 = fmaf(vv, qq.z, m2);
        m3 = fmaf(vv, qq.w, m3);
    }
    float4* Pb = (float4*)(P_ws + ((size_t)b * NBLK + blockIdx.x) * CDIM * CDIM);
    Pb[cv * (CDIM / 4) + (cq0 >> 2)] = make_float4(m0, m1, m2, m3);
}

// ---------------------------------------------------------------------------
// Kernel 2: reduce M partials in-block -> y = M k + x -> BN partials.
// (R11-proven: in-block P reduction, no k_reduceM dispatch.)
// ---------------------------------------------------------------------------
__global__ __launch_bounds__(1024, 4) void k_spatial(
    const float* __restrict__ x, const float* __restrict__ k_ws,
    const float* __restrict__ P_ws, float* __restrict__ y_ws,
    float* __restrict__ spB)
{
    __shared__ alignas(16) float kl[CDIM][XS];
    __shared__ alignas(16) float Ms[CDIM][XS];
    const int b   = blockIdx.y;
    const int l0  = blockIdx.x * TL;
    const int tid = threadIdx.x;
    const int c   = tid >> 4;
    const int p0  = (tid & 15) << 2;

    // reduce the 64 M-partials for batch b; thread owns float4 element 'tid'
    {
        const float4* Pf4 = (const float4*)P_ws + (size_t)b * NBLK * (CDIM * CDIM / 4);
        float4 s0 = make_float4(0, 0, 0, 0), s1 = s0, s2 = s0, s3 = s0;
        for (int blk = 0; blk < NBLK; blk += 4) {
            float4 p0v = Pf4[(size_t)(blk + 0) * (CDIM * CDIM / 4) + tid];
            float4 p1v = Pf4[(size_t)(blk + 1) * (CDIM * CDIM / 4) + tid];
            float4 p2v = Pf4[(size_t)(blk + 2) * (CDIM * CDIM / 4) + tid];
            float4 p3v = Pf4[(size_t)(blk + 3) * (CDIM * CDIM / 4) + tid];
            s0.x += p0v.x; s0.y += p0v.y; s0.z += p0v.z; s0.w += p0v.w;
            s1.x += p1v.x; s1.y += p1v.y; s1.z += p1v.z; s1.w += p1v.w;
            s2.x += p2v.x; s2.y += p2v.y; s2.z += p2v.z; s2.w += p2v.w;
            s3.x += p3v.x; s3.y += p3v.y; s3.z += p3v.z; s3.w += p3v.w;
        }
        *reinterpret_cast<float4*>(&Ms[c][p0]) =
            make_float4((s0.x + s1.x) + (s2.x + s3.x),
                        (s0.y + s1.y) + (s2.y + s3.y),
                        (s0.z + s1.z) + (s2.z + s3.z),
                        (s0.w + s1.w) + (s2.w + s3.w));
    }
    *reinterpret_cast<float4*>(&kl[c][p0]) =
        *reinterpret_cast<const float4*>(k_ws + ((size_t)b * CDIM + c) * LDIM + l0 + p0);
    __syncthreads();

    float4 acc = *reinterpret_cast<const float4*>(
        x + ((size_t)b * CDIM + c) * LDIM + l0 + p0);
#pragma unroll 2
    for (int i4 = 0; i4 < 16; ++i4) {
        float4 mv = *reinterpret_cast<const float4*>(&Ms[c][i4 * 4]);
        float4 k0 = *reinterpret_cast<const float4*>(&kl[i4 * 4 + 0][p0]);
        float4 k1 = *reinterpret_cast<const float4*>(&kl[i4 * 4 + 1][p0]);
        float4 k2 = *reinterpret_cast<const float4*>(&kl[i4 * 4 + 2][p0]);
        float4 k3 = *reinterpret_cast<const float4*>(&kl[i4 * 4 + 3][p0]);
        acc.x = fmaf(mv.x, k0.x, fmaf(mv.y, k1.x, fmaf(mv.z, k2.x, fmaf(mv.w, k3.x, acc.x))));
        acc.y = fmaf(mv.x, k0.y, fmaf(mv.y, k1.y, fmaf(mv.z, k2.y, fmaf(mv.w, k3.y, acc.y))));
        acc.z = fmaf(mv.x, k0.z, fmaf(mv.y, k1.z, fmaf(mv.z, k2.z, fmaf(mv.w, k3.z, acc.z))));
        acc.w = fmaf(mv.x, k0.w, fmaf(mv.y, k1.w, fmaf(mv.z, k2.w, fmaf(mv.w, k3.w, acc.w))));
    }
    *reinterpret_cast<float4*>(y_ws + ((size_t)b * CDIM + c) * LDIM + l0 + p0) = acc;

    const int blk = blockIdx.y * NBLK + blockIdx.x;
    float s  = (acc.x + acc.y) + (acc.z + acc.w);
    float s2 = fmaf(acc.x, acc.x, fmaf(acc.y, acc.y,
               fmaf(acc.z, acc.z, acc.w * acc.w)));
    for (int off = 8; off; off >>= 1) {
        s  += __shfl_down(s, off);
        s2 += __shfl_down(s2, off);
    }
    if ((tid & 15) == 0) {
        spB[(size_t)blk * (2 * CDIM) + c] = s;
        spB[(size_t)blk * (2 * CDIM) + CDIM + c] = s2;
    }
}

// ---------------------------------------------------------------------------
// Kernel 3 (merged reduceS+norm): each of 256 blocks redundantly reduces
// spB [256][128] in LDS, then normalizes its 1024-float4 slice of y.
// ---------------------------------------------------------------------------
__global__ __launch_bounds__(1024) void k_normS(
    const float* __restrict__ y_ws, const float* __restrict__ spB,
    const float* __restrict__ gamma, const float* __restrict__ beta,
    float* __restrict__ out)
{
    __shared__ float red[8][128];
    __shared__ float sums2[2 * CDIM];
    const int tid = threadIdx.x;

    {   // reduce spB
        const int t = tid & 127;
        const int g = tid >> 7;          // 0..7, 32 rows each
        float s0 = 0.f, s1 = 0.f;
        const int r0 = g * 32;
        for (int r = r0; r < r0 + 32; r += 2) {
            s0 += spB[(size_t)(r + 0) * (2 * CDIM) + t];
            s1 += spB[(size_t)(r + 1) * (2 * CDIM) + t];
        }
        red[g][t] = s0 + s1;
    }
    __syncthreads();
    if (tid < 128)
        sums2[tid] = ((red[0][tid] + red[1][tid]) + (red[2][tid] + red[3][tid]))
                   + ((red[4][tid] + red[5][tid]) + (red[6][tid] + red[7][tid]));
    __syncthreads();

    const int idx = blockIdx.x * 1024 + tid;       // float4 index
    const int c   = (idx >> 10) & (CDIM - 1);      // 1024 float4 per (b,c) row
    const float inv = 1.f / (float)(NB * LDIM);
    float mean = sums2[c] * inv;
    float var  = fmaf(-mean, mean, sums2[CDIM + c] * inv);
    float rstd = 1.f / sqrtf(var + EPS);
    float g    = gamma[c] * rstd;
    float bb   = fmaf(-mean, g, beta[c]);

    float4 v = ((const float4*)y_ws)[idx];
    float4 o;
    o.x = fmaf(v.x, g, bb);
    o.y = fmaf(v.y, g, bb);
    o.z = fmaf(v.z, g, bb);
    o.w = fmaf(v.w, g, bb);
    ((float4*)out)[idx] = o;
}

// ---------------------------------------------------------------------------
extern "C" void kernel_launch(void* const* d_in, const int* in_sizes, int n_in,
                              void* d_out, int out_size, void* d_ws, size_t ws_size,
                              hipStream_t stream)
{
    const float* x      = (const float*)d_in[0];
    const float* conv_w = (const float*)d_in[1];
    const float* conv_b = (const float*)d_in[2];
    const float* wq     = (const float*)d_in[3];
    const float* bq     = (const float*)d_in[4];
    const float* wk     = (const float*)d_in[5];
    const float* bk     = (const float*)d_in[6];
    const float* wv     = (const float*)d_in[7];
    const float* bv     = (const float*)d_in[8];
    const float* gamma  = (const float*)d_in[9];
    const float* beta   = (const float*)d_in[10];

    float* ws   = (float*)d_ws;
    float* k_ws = ws + K_OFF;
    float* y_ws = ws + Y_OFF;
    float* P_ws = ws + P_OFF;
    float* spB  = ws + SP_OFF;

    dim3 grid(NBLK, NB);
    k_front<<<grid, 1024, 0, stream>>>(x, conv_w, conv_b, wq, bq, wk, bk,
                                       wv, bv, k_ws, P_ws);
    k_spatial<<<grid, 1024, 0, stream>>>(x, k_ws, P_ws, y_ws, spB);
    k_normS<<<NB * CDIM * LDIM / 4096, 1024, 0, stream>>>(y_ws, spB, gamma, beta,
                                                          (float*)d_out);
}